// Round 10
// baseline (1491.261 us; speedup 1.0000x reference)
//
#include <hip/hip_runtime.h>
#include <stdint.h>

#define TWO_PI_F 6.28318530717958647692f
#define INV_2PI_F 0.15915494309189535f
#define EPSF 1e-6f
#define DTF 0.01f
#define KCOUP 2.0f
#define CPL (DTF * KCOUP * INV_2PI_F)   // coupling gain in revolutions domain

// ---- GEMM geometry ----
#define BM 256                    // 8 waves x 32 rows
#define BN 96
#define GTHREADS 512
#define KITERS 32                 // 2048 / 64
#define NTILES 7                  // 672 / 96, exact
#define B_TILE_BYTES (BN * 128)   // 12288 (96 cols x 128B per 64-K chunk)
#define WCHUNK (672 * 128)        // 86016 bytes per K-chunk of B image
#define W_IMG_BYTES ((size_t)KITERS * WCHUNK)   // 2,752,512
#define WS_NEED W_IMG_BYTES

typedef __attribute__((ext_vector_type(8)))  __bf16         bf16x8;
typedef __attribute__((ext_vector_type(8)))  unsigned short ushort8v;
typedef __attribute__((ext_vector_type(16))) float          f32x16;

__device__ __forceinline__ unsigned short f2bf(float f) {
  unsigned u = __builtin_bit_cast(unsigned, f);
  u = (u + 0x7FFFu + ((u >> 16) & 1u)) >> 16;   // RNE
  return (unsigned short)u;
}

// pack 2 f32 -> 2 bf16 (RNE), S0 -> low16, S1 -> high16
__device__ __forceinline__ unsigned cvtpk(float lo, float hi) {
  unsigned r;
  asm("v_cvt_pk_bf16_f32 %0, %1, %2" : "=v"(r) : "v"(lo), "v"(hi));
  return r;
}

// ---------- prep_w: W (f32) -> swizzled bf16 image [t][col][slot*16B] ----------
__global__ void prep_w(const float* __restrict__ Wd, const float* __restrict__ Wt,
                       const float* __restrict__ Wg, char* __restrict__ wbB) {
  int id = blockIdx.x * 256 + threadIdx.x;      // 672 * 64 total
  if (id >= 672 * 64) return;
  int col = id >> 6;
  int rem = id & 63, t = rem >> 1, h = rem & 1;
  const float* src = (col < 32)  ? Wd + (size_t)col * 2048
                   : (col < 160) ? Wt + (size_t)(col - 32) * 2048
                                 : Wg + (size_t)(col - 160) * 2048;
  src += t * 64 + h * 32;
  char* dst = wbB + ((size_t)t * 672 + col) * 128;
  #pragma unroll
  for (int s4 = 0; s4 < 4; s4++) {
    float4 a = ((const float4*)src)[s4 * 2];
    float4 b = ((const float4*)src)[s4 * 2 + 1];
    ushort8v v;
    v[0] = f2bf(a.x); v[1] = f2bf(a.y); v[2] = f2bf(a.z); v[3] = f2bf(a.w);
    v[4] = f2bf(b.x); v[5] = f2bf(b.y); v[6] = f2bf(b.z); v[7] = f2bf(b.w);
    int slot = (h * 4 + s4) ^ (col & 7);
    *(ushort8v*)(dst + slot * 16) = v;
  }
}

// ---------- K1: 512-thr / BM=256, full-occupancy latency-hiding gemm ----------
__launch_bounds__(GTHREADS, 8)
__global__ void gemm_f(const float* __restrict__ x, const char* __restrict__ wbB,
                       float* __restrict__ z) {
  __shared__ __align__(16) char smem[2 * B_TILE_BYTES];   // 24 KB

  const int tid = threadIdx.x;
  const int wid = tid >> 6, lane = tid & 63;
  const bool stager = (wid < 4);                // waves 0-3 stage B (tid < 256)

  // XCD-aware: 896 blocks all co-resident; each XCD owns 16 exclusive 256-row
  // panels; the 7 n-tiles of a panel sit on one XCD -> x panel L2-shared.
  const int bid = blockIdx.x;
  const int xcd = bid & 7, j = bid >> 3;
  const int panel = xcd * ((gridDim.x / NTILES) >> 3) + j / NTILES;
  const int n = j % NTILES;
  const size_t row0 = (size_t)panel * BM;

  f32x16 acc[3];
  #pragma unroll
  for (int f = 0; f < 3; f++)
    #pragma unroll
    for (int jj = 0; jj < 16; jj++) acc[f][jj] = 0.f;

  const char* bsrc0 = wbB + n * B_TILE_BYTES;
  // A source: row = row0 + wid*32 + (lane&31); k-half offset (lane>>5)*8.
  // MFMA s4 fragment: k = t*64 + s4*16 + hk*8 .. +7  (slot sl = s4*2+hk).
  const float* abase = x + (row0 + wid * 32 + (lane & 31)) * 2048 + (lane >> 5) * 8;

#define STAGE_B(buf, t)                                                       \
  { if (stager) {                                                             \
      const char* bsrc = bsrc0 + (size_t)(t) * WCHUNK;                        \
      _Pragma("unroll")                                                       \
      for (int rnd = 0; rnd < 3; rnd++) {                                     \
        int off = rnd * 4096 + tid * 16;                                      \
        __builtin_amdgcn_global_load_lds(                                     \
          (const __attribute__((address_space(1))) void*)(bsrc + off),        \
          (__attribute__((address_space(3))) void*)(smem + (buf) * B_TILE_BYTES + off), \
          16, 0, 0); } } }

#define LOADA(arr, t)                                                         \
  { _Pragma("unroll")                                                         \
    for (int s4 = 0; s4 < 4; s4++) {                                          \
      const float4* ap = (const float4*)(abase + (t) * 64 + s4 * 16);         \
      arr[s4 * 2] = ap[0]; arr[s4 * 2 + 1] = ap[1]; } }

#define CVTA(arr)                                                             \
  { _Pragma("unroll")                                                         \
    for (int s4 = 0; s4 < 4; s4++) {                                          \
      unsigned d0 = cvtpk(arr[s4*2].x, arr[s4*2].y);                          \
      unsigned d1 = cvtpk(arr[s4*2].z, arr[s4*2].w);                          \
      unsigned d2 = cvtpk(arr[s4*2+1].x, arr[s4*2+1].y);                      \
      unsigned d3 = cvtpk(arr[s4*2+1].z, arr[s4*2+1].w);                      \
      uint4 u = {d0, d1, d2, d3};                                             \
      abf[s4] = __builtin_bit_cast(bf16x8, u); } }

#define MFMA12(cur)                                                           \
  { const char* Bs = smem + (cur) * B_TILE_BYTES;                             \
    _Pragma("unroll")                                                         \
    for (int s4 = 0; s4 < 4; s4++) {                                          \
      int sl = s4 * 2 + (lane >> 5);                                          \
      _Pragma("unroll")                                                       \
      for (int fn = 0; fn < 3; fn++) {                                        \
        int c = fn * 32 + (lane & 31);                                        \
        bf16x8 bfr = __builtin_bit_cast(bf16x8,                               \
            *(const ushort8v*)(Bs + c * 128 + ((sl ^ (c & 7)) << 4)));        \
        acc[fn] = __builtin_amdgcn_mfma_f32_32x32x16_bf16(abf[s4], bfr, acc[fn], 0, 0, 0); } } }

// steady-state outstanding at wait point:
//   stager:     B(t)3 + A(t+1)8 + B(t+1)3 + A(t+2)8 = 22 -> vmcnt(11) retires B(t),A(t+1)
//   non-stager: A(t+1)8 + A(t+2)8 = 16                   -> vmcnt(8)  retires A(t+1)
#define BODY(t, AL, AC, cur)                                                  \
  {                                                                           \
    if ((t) + 2 < KITERS) { LOADA(AL, (t) + 2); }                             \
    if ((t) >= KITERS - 2) { asm volatile("s_waitcnt vmcnt(0)" ::: "memory"); } \
    else if (stager)       { asm volatile("s_waitcnt vmcnt(11)" ::: "memory"); } \
    else                   { asm volatile("s_waitcnt vmcnt(8)" ::: "memory"); } \
    __builtin_amdgcn_s_barrier();                                             \
    __builtin_amdgcn_sched_barrier(0);                                        \
    MFMA12(cur);                                                              \
    if ((t) + 1 < KITERS) { CVTA(AC); }                                       \
    __builtin_amdgcn_sched_barrier(0);                                        \
    __builtin_amdgcn_s_barrier();                                             \
    __builtin_amdgcn_sched_barrier(0);                                        \
    if ((t) + 2 < KITERS) { STAGE_B(cur, (t) + 2); }                          \
  }

  float4 aFA[8], aFB[8];
  bf16x8 abf[4];

  // prologue: establish invariant [B(t), A(t+1), B(t+1)] outstanding at loop top
  LOADA(aFA, 0);            // A(0): 8
  STAGE_B(0, 0);            // B(0): +3 (stagers)
  LOADA(aFB, 1);            // A(1): +8
  if (stager) { asm volatile("s_waitcnt vmcnt(11)" ::: "memory"); }
  else        { asm volatile("s_waitcnt vmcnt(8)"  ::: "memory"); }
  CVTA(aFA);                // abf = A(0), already retired
  STAGE_B(1, 1);            // B(1): +3 (stagers)

  for (int tt = 0; tt < KITERS; tt += 2) {
    BODY(tt,     aFA, aFB, 0);   // load A(tt+2)->aFA, cvt A(tt+1) from aFB
    BODY(tt + 1, aFB, aFA, 1);   // load A(tt+3)->aFB, cvt A(tt+2) from aFA
  }
#undef STAGE_B
#undef LOADA
#undef CVTA
#undef MFMA12
#undef BODY

  #pragma unroll
  for (int fn = 0; fn < 3; fn++) {
    int col = n * 96 + fn * 32 + (lane & 31);
    #pragma unroll
    for (int reg = 0; reg < 16; reg++) {
      int row = wid * 32 + (reg & 3) + ((reg >> 2) << 3) + ((lane >> 5) << 2);
      z[(row0 + row) * 672 + col] = acc[fn][reg];
    }
  }
}

// ---------- wave-wide f32 sum: 4 DPP levels + ds_swizzle xor16 + shfl xor32 ----------
__device__ __forceinline__ float wave_sum(float v) {
  v += __builtin_bit_cast(float, __builtin_amdgcn_update_dpp(
         0, __builtin_bit_cast(int, v), 0xB1, 0xF, 0xF, true));   // quad_perm xor1
  v += __builtin_bit_cast(float, __builtin_amdgcn_update_dpp(
         0, __builtin_bit_cast(int, v), 0x4E, 0xF, 0xF, true));   // quad_perm xor2
  v += __builtin_bit_cast(float, __builtin_amdgcn_update_dpp(
         0, __builtin_bit_cast(int, v), 0x141, 0xF, 0xF, true));  // row_half_mirror
  v += __builtin_bit_cast(float, __builtin_amdgcn_update_dpp(
         0, __builtin_bit_cast(int, v), 0x140, 0xF, 0xF, true));  // row_mirror
  v += __builtin_bit_cast(float, __builtin_amdgcn_ds_swizzle(
         __builtin_bit_cast(int, v), 0x401F));                    // xor16
  v += __shfl_xor(v, 32);                                         // cross-32
  return v;
}

// ---------- K2: Kuramoto dynamics + in-place scale of d_out ----------
#define ZSTR 164
#define DROWS 32
__launch_bounds__(256, 6)
__global__ void dyn_scale(float* __restrict__ z,
                          const float* __restrict__ pdt_p,
                          const float* __restrict__ ptg_p) {
  __shared__ float zdt[DROWS * ZSTR];
  __shared__ float Fbuf[2 * DROWS];
  const int tid = threadIdx.x;
  const int wid = tid >> 6, lane = tid & 63;
  const size_t row0 = (size_t)blockIdx.x * DROWS;

  for (int i = tid; i < DROWS * 40; i += 256) {
    int row = i / 40, c4 = i - row * 40;
    float4 v = *(const float4*)(z + (row0 + row) * 672 + c4 * 4);
    *(float4*)(&zdt[row * ZSTR + c4 * 4]) = v;
  }
  __syncthreads();

  const float pdt = fminf(fmaxf(pdt_p[0], 0.f), 1.f);
  const float ptg = fminf(fmaxf(ptg_p[0], 0.f), 1.f);

  for (int rr = 0; rr < 8; rr++) {
    int row = wid * 8 + rr;
    // phases in revolutions: q = p / 2π;  sin(p) = v_sin(fract(q))
    float pd  = ((lane < 32) ? zdt[row * ZSTR + lane] : 0.f) * INV_2PI_F;
    float pt0 = zdt[row * ZSTR + 32 + lane] * INV_2PI_F;
    float pt1 = zdt[row * ZSTR + 96 + lane] * INV_2PI_F;
    float Ft = 1.f, Fg = 1.f;
    for (int s = 0; s < 10; s++) {
      float qd = pd - floorf(pd), q0 = pt0 - floorf(pt0), q1 = pt1 - floorf(pt1);
      float sd, cd, s0, c0, s1, c1;
      asm("v_sin_f32 %0, %1" : "=v"(sd) : "v"(qd));
      asm("v_cos_f32 %0, %1" : "=v"(cd) : "v"(qd));
      asm("v_sin_f32 %0, %1" : "=v"(s0) : "v"(q0));
      asm("v_cos_f32 %0, %1" : "=v"(c0) : "v"(q0));
      asm("v_sin_f32 %0, %1" : "=v"(s1) : "v"(q1));
      asm("v_cos_f32 %0, %1" : "=v"(c1) : "v"(q1));
      float Cd = wave_sum((lane < 32) ? cd : 0.f) * (1.f / 32.f);
      float Sd = wave_sum((lane < 32) ? sd : 0.f) * (1.f / 32.f);
      float Ct = wave_sum(c0 + c1) * (1.f / 128.f);
      float St = wave_sum(s0 + s1) * (1.f / 128.f);
      pd  += DTF * 2.f + CPL * (Sd * cd - Cd * sd);
      pt0 += DTF * 6.f + CPL * (St * c0 - Ct * s0);
      pt1 += DTF * 6.f + CPL * (St * c1 - Ct * s1);
      float rdm = sqrtf(Cd * Cd + Sd * Sd) + EPSF;
      float rtm = sqrtf(Ct * Ct + St * St) + EPSF;
      Ft *= (1.f + DTF * pdt * (Cd / rdm));
      Fg *= (1.f + DTF * ptg * (Ct / rtm));
    }
    if (lane == 0) { Fbuf[row] = Ft; Fbuf[DROWS + row] = Fg; }
  }
  __syncthreads();

  for (int i = tid; i < DROWS * 168; i += 256) {
    int row = i / 168, c4 = i - row * 168;
    float4* p = (float4*)(z + (row0 + row) * 672 + c4 * 4);
    float4 v = *p;
    float f = (c4 < 8) ? 1.f : (c4 < 40 ? Fbuf[row] : Fbuf[DROWS + row]);
    v.x = fmaxf(fmaxf(fabsf(v.x), EPSF) * f, EPSF);
    v.y = fmaxf(fmaxf(fabsf(v.y), EPSF) * f, EPSF);
    v.z = fmaxf(fmaxf(fabsf(v.z), EPSF) * f, EPSF);
    v.w = fmaxf(fmaxf(fabsf(v.w), EPSF) * f, EPSF);
    *p = v;
  }
}

extern "C" void kernel_launch(void* const* d_in, const int* in_sizes, int n_in,
                              void* d_out, int out_size, void* d_ws, size_t ws_size,
                              hipStream_t stream) {
  const float* x   = (const float*)d_in[0];
  const float* Wd  = (const float*)d_in[1];
  const float* Wt  = (const float*)d_in[2];
  const float* Wg  = (const float*)d_in[3];
  const float* pdt = (const float*)d_in[4];
  const float* ptg = (const float*)d_in[5];
  float* outp = (float*)d_out;
  char* wbB = (char*)d_ws;

  if (ws_size < WS_NEED) return;

  const int Brows = in_sizes[0] / 2048;           // 32768
  prep_w<<<(672 * 64 + 255) / 256, 256, 0, stream>>>(Wd, Wt, Wg, wbB);
  gemm_f<<<(Brows / BM) * NTILES, GTHREADS, 0, stream>>>(x, wbB, outp);
  dyn_scale<<<Brows / DROWS, 256, 0, stream>>>(outp, pdt, ptg);
}

// Round 11
// 292.896 us; speedup vs baseline: 5.0914x; 5.0914x over previous
//
#include <hip/hip_runtime.h>
#include <stdint.h>

#define TWO_PI_F 6.28318530717958647692f
#define INV_2PI_F 0.15915494309189535f
#define EPSF 1e-6f
#define DTF 0.01f
#define KCOUP 2.0f
#define CPL (DTF * KCOUP * INV_2PI_F)   // coupling gain in revolutions domain

// ---- GEMM geometry (round-4 proven config) ----
#define BM 128
#define BN 96
#define KITERS 32                 // 2048 / 64, BK=64
#define NTILES 7                  // 672 / 96, exact
#define GTHREADS 256
#define B_TILE_BYTES (BN * 128)   // 12288
#define A_TILE_BYTES (BM * 128)   // 16384 (bf16)
#define WCHUNK (672 * 128)        // 86016 bytes per K-chunk of B image
#define W_IMG_BYTES ((size_t)KITERS * WCHUNK)          // 2,752,512
#define XB_BYTES ((size_t)32768 * 2048 * 2)            // 134,217,728
#define WS_NEED (W_IMG_BYTES + XB_BYTES)

typedef __attribute__((ext_vector_type(8)))  __bf16         bf16x8;
typedef __attribute__((ext_vector_type(8)))  unsigned short ushort8v;
typedef __attribute__((ext_vector_type(16))) float          f32x16;

__device__ __forceinline__ unsigned short f2bf(float f) {
  unsigned u = __builtin_bit_cast(unsigned, f);
  u = (u + 0x7FFFu + ((u >> 16) & 1u)) >> 16;   // RNE
  return (unsigned short)u;
}

// ---------- prep_w: W (f32) -> swizzled bf16 image [t][col][slot*16B] ----------
__global__ void prep_w(const float* __restrict__ Wd, const float* __restrict__ Wt,
                       const float* __restrict__ Wg, char* __restrict__ wbB) {
  int id = blockIdx.x * 256 + threadIdx.x;      // 672 * 64 total
  if (id >= 672 * 64) return;
  int col = id >> 6;
  int rem = id & 63, t = rem >> 1, h = rem & 1;
  const float* src = (col < 32)  ? Wd + (size_t)col * 2048
                   : (col < 160) ? Wt + (size_t)(col - 32) * 2048
                                 : Wg + (size_t)(col - 160) * 2048;
  src += t * 64 + h * 32;
  char* dst = wbB + ((size_t)t * 672 + col) * 128;
  #pragma unroll
  for (int s4 = 0; s4 < 4; s4++) {
    float4 a = ((const float4*)src)[s4 * 2];
    float4 b = ((const float4*)src)[s4 * 2 + 1];
    ushort8v v;
    v[0] = f2bf(a.x); v[1] = f2bf(a.y); v[2] = f2bf(a.z); v[3] = f2bf(a.w);
    v[4] = f2bf(b.x); v[5] = f2bf(b.y); v[6] = f2bf(b.z); v[7] = f2bf(b.w);
    int slot = (h * 4 + s4) ^ (col & 7);
    *(ushort8v*)(dst + slot * 16) = v;
  }
}

// ---------- prep_x: x f32 -> plain row-major bf16 image (L3-resident 134 MB) ----------
__global__ void prep_x(const float* __restrict__ x, unsigned short* __restrict__ xb,
                       int n8) {
  int i = blockIdx.x * 256 + threadIdx.x;       // one thread per 8 elems
  if (i >= n8) return;
  const float4* s = (const float4*)x + (size_t)i * 2;
  float4 a = s[0], b = s[1];
  ushort8v v;
  v[0] = f2bf(a.x); v[1] = f2bf(a.y); v[2] = f2bf(a.z); v[3] = f2bf(a.w);
  v[4] = f2bf(b.x); v[5] = f2bf(b.y); v[6] = f2bf(b.z); v[7] = f2bf(b.w);
  *(ushort8v*)(xb + (size_t)i * 8) = v;
}

// ---------- K1 (round-4 proven): both operands via global_load_lds ----------
__launch_bounds__(GTHREADS, 4)
__global__ void gemm(const unsigned short* __restrict__ xb,
                     const char* __restrict__ wbB, float* __restrict__ z) {
  __shared__ __align__(16) char smem[B_TILE_BYTES + A_TILE_BYTES];
  char* Bs = smem;
  char* As = smem + B_TILE_BYTES;

  const int tid = threadIdx.x;
  const int wid = tid >> 6, lane = tid & 63;

  // XCD-aware: each XCD owns 32 exclusive row panels; 7 n-tiles of a panel adjacent
  const int bid = blockIdx.x;
  const int xcd = bid & 7, j = bid >> 3;
  const int panel = xcd * 32 + j / NTILES;
  const int n = j % NTILES;
  const size_t row0 = (size_t)panel * BM;

  f32x16 acc[3];
  #pragma unroll
  for (int f = 0; f < 3; f++)
    #pragma unroll
    for (int jj = 0; jj < 16; jj++) acc[f][jj] = 0.f;

  // A gll source: thread stages 16B; dest row = rnd*32 + (tid>>3), slot = tid&7
  const int arow_s = tid >> 3;
  const int aslot  = (tid & 7) ^ (arow_s & 7);          // row&7 invariant across rounds
  const unsigned short* asrc0 = xb + (row0 + arow_s) * 2048 + aslot * 8;

  // frag read bases
  const int arf = wid * 32 + (lane & 31);
  const char* afbase = As + arf * 128;
  const int arf7 = arf & 7;

  for (int t = 0; t < KITERS; t++) {
    __syncthreads();                              // prev compute done, LDS free
    {
      const char* bsrc = wbB + (size_t)t * WCHUNK + n * B_TILE_BYTES;
      #pragma unroll
      for (int rnd = 0; rnd < 3; rnd++) {
        int off = rnd * 4096 + tid * 16;
        __builtin_amdgcn_global_load_lds(
            (const __attribute__((address_space(1))) void*)(bsrc + off),
            (__attribute__((address_space(3))) void*)(Bs + off), 16, 0, 0);
      }
      const unsigned short* asrc = asrc0 + t * 64;
      #pragma unroll
      for (int rnd = 0; rnd < 4; rnd++) {
        __builtin_amdgcn_global_load_lds(
            (const __attribute__((address_space(1))) void*)(asrc + (size_t)rnd * 32 * 2048),
            (__attribute__((address_space(3))) void*)(As + rnd * 4096 + tid * 16), 16, 0, 0);
      }
    }
    __syncthreads();                              // staged tiles visible
    #pragma unroll
    for (int k16 = 0; k16 < 4; k16++) {
      int sl = k16 * 2 + (lane >> 5);
      bf16x8 af = __builtin_bit_cast(bf16x8,
          *(const ushort8v*)(afbase + ((sl ^ arf7) << 4)));
      #pragma unroll
      for (int fn = 0; fn < 3; fn++) {
        int c = fn * 32 + (lane & 31);
        bf16x8 bfr = __builtin_bit_cast(bf16x8,
            *(const ushort8v*)(Bs + c * 128 + ((sl ^ (c & 7)) << 4)));
        acc[fn] = __builtin_amdgcn_mfma_f32_32x32x16_bf16(af, bfr, acc[fn], 0, 0, 0);
      }
    }
  }

  #pragma unroll
  for (int fn = 0; fn < 3; fn++) {
    int col = n * 96 + fn * 32 + (lane & 31);
    #pragma unroll
    for (int reg = 0; reg < 16; reg++) {
      int row = wid * 32 + (reg & 3) + ((reg >> 2) << 3) + ((lane >> 5) << 2);
      z[(row0 + row) * 672 + col] = acc[fn][reg];
    }
  }
}

// ---------- wave-wide f32 sum: 4 DPP levels + ds_swizzle xor16 + shfl xor32 ----------
__device__ __forceinline__ float wave_sum(float v) {
  v += __builtin_bit_cast(float, __builtin_amdgcn_update_dpp(
         0, __builtin_bit_cast(int, v), 0xB1, 0xF, 0xF, true));   // quad_perm xor1
  v += __builtin_bit_cast(float, __builtin_amdgcn_update_dpp(
         0, __builtin_bit_cast(int, v), 0x4E, 0xF, 0xF, true));   // quad_perm xor2
  v += __builtin_bit_cast(float, __builtin_amdgcn_update_dpp(
         0, __builtin_bit_cast(int, v), 0x141, 0xF, 0xF, true));  // row_half_mirror
  v += __builtin_bit_cast(float, __builtin_amdgcn_update_dpp(
         0, __builtin_bit_cast(int, v), 0x140, 0xF, 0xF, true));  // row_mirror
  v += __builtin_bit_cast(float, __builtin_amdgcn_ds_swizzle(
         __builtin_bit_cast(int, v), 0x401F));                    // xor16
  v += __shfl_xor(v, 32);                                         // cross-32
  return v;
}

// ---------- K2: Kuramoto dynamics + in-place scale of d_out ----------
#define ZSTR 164
#define DROWS 32
__launch_bounds__(256, 6)
__global__ void dyn_scale(float* __restrict__ z,
                          const float* __restrict__ pdt_p,
                          const float* __restrict__ ptg_p) {
  __shared__ float zdt[DROWS * ZSTR];
  __shared__ float Fbuf[2 * DROWS];
  const int tid = threadIdx.x;
  const int wid = tid >> 6, lane = tid & 63;
  const size_t row0 = (size_t)blockIdx.x * DROWS;

  for (int i = tid; i < DROWS * 40; i += 256) {
    int row = i / 40, c4 = i - row * 40;
    float4 v = *(const float4*)(z + (row0 + row) * 672 + c4 * 4);
    *(float4*)(&zdt[row * ZSTR + c4 * 4]) = v;
  }
  __syncthreads();

  const float pdt = fminf(fmaxf(pdt_p[0], 0.f), 1.f);
  const float ptg = fminf(fmaxf(ptg_p[0], 0.f), 1.f);

  for (int rr = 0; rr < 8; rr++) {
    int row = wid * 8 + rr;
    // phases in revolutions: q = p / 2π;  sin(p) = v_sin(fract(q))
    float pd  = ((lane < 32) ? zdt[row * ZSTR + lane] : 0.f) * INV_2PI_F;
    float pt0 = zdt[row * ZSTR + 32 + lane] * INV_2PI_F;
    float pt1 = zdt[row * ZSTR + 96 + lane] * INV_2PI_F;
    float Ft = 1.f, Fg = 1.f;
    for (int s = 0; s < 10; s++) {
      float qd = pd - floorf(pd), q0 = pt0 - floorf(pt0), q1 = pt1 - floorf(pt1);
      float sd, cd, s0, c0, s1, c1;
      asm("v_sin_f32 %0, %1" : "=v"(sd) : "v"(qd));
      asm("v_cos_f32 %0, %1" : "=v"(cd) : "v"(qd));
      asm("v_sin_f32 %0, %1" : "=v"(s0) : "v"(q0));
      asm("v_cos_f32 %0, %1" : "=v"(c0) : "v"(q0));
      asm("v_sin_f32 %0, %1" : "=v"(s1) : "v"(q1));
      asm("v_cos_f32 %0, %1" : "=v"(c1) : "v"(q1));
      float Cd = wave_sum((lane < 32) ? cd : 0.f) * (1.f / 32.f);
      float Sd = wave_sum((lane < 32) ? sd : 0.f) * (1.f / 32.f);
      float Ct = wave_sum(c0 + c1) * (1.f / 128.f);
      float St = wave_sum(s0 + s1) * (1.f / 128.f);
      pd  += DTF * 2.f + CPL * (Sd * cd - Cd * sd);
      pt0 += DTF * 6.f + CPL * (St * c0 - Ct * s0);
      pt1 += DTF * 6.f + CPL * (St * c1 - Ct * s1);
      float rdm = sqrtf(Cd * Cd + Sd * Sd) + EPSF;
      float rtm = sqrtf(Ct * Ct + St * St) + EPSF;
      Ft *= (1.f + DTF * pdt * (Cd / rdm));
      Fg *= (1.f + DTF * ptg * (Ct / rtm));
    }
    if (lane == 0) { Fbuf[row] = Ft; Fbuf[DROWS + row] = Fg; }
  }
  __syncthreads();

  // scale: cols 0..159 come from the LDS copy (no global re-read); rest from global
  for (int i = tid; i < DROWS * 168; i += 256) {
    int row = i / 168, c4 = i - row * 168;
    float4* p = (float4*)(z + (row0 + row) * 672 + c4 * 4);
    float4 v = (c4 < 40) ? *(const float4*)(&zdt[row * ZSTR + c4 * 4]) : *p;
    float f = (c4 < 8) ? 1.f : (c4 < 40 ? Fbuf[row] : Fbuf[DROWS + row]);
    v.x = fmaxf(fmaxf(fabsf(v.x), EPSF) * f, EPSF);
    v.y = fmaxf(fmaxf(fabsf(v.y), EPSF) * f, EPSF);
    v.z = fmaxf(fmaxf(fabsf(v.z), EPSF) * f, EPSF);
    v.w = fmaxf(fmaxf(fabsf(v.w), EPSF) * f, EPSF);
    *p = v;
  }
}

extern "C" void kernel_launch(void* const* d_in, const int* in_sizes, int n_in,
                              void* d_out, int out_size, void* d_ws, size_t ws_size,
                              hipStream_t stream) {
  const float* x   = (const float*)d_in[0];
  const float* Wd  = (const float*)d_in[1];
  const float* Wt  = (const float*)d_in[2];
  const float* Wg  = (const float*)d_in[3];
  const float* pdt = (const float*)d_in[4];
  const float* ptg = (const float*)d_in[5];
  float* outp = (float*)d_out;
  char* wbB = (char*)d_ws;

  if (ws_size < WS_NEED) return;   // harness provides ~1 GB

  const int Brows = in_sizes[0] / 2048;           // 32768
  unsigned short* xb = (unsigned short*)(wbB + W_IMG_BYTES);
  const int n8 = Brows * 256;                     // elems / 8

  prep_w<<<(672 * 64 + 255) / 256, 256, 0, stream>>>(Wd, Wt, Wg, wbB);
  prep_x<<<(n8 + 255) / 256, 256, 0, stream>>>(x, xb, n8);
  gemm<<<(Brows / BM) * NTILES, GTHREADS, 0, stream>>>(xb, wbB, outp);
  dyn_scale<<<Brows / DROWS, 256, 0, stream>>>(outp, pdt, ptg);
}

// Round 12
// 265.715 us; speedup vs baseline: 5.6123x; 1.1023x over previous
//
#include <hip/hip_runtime.h>
#include <stdint.h>

#define TWO_PI_F 6.28318530717958647692f
#define INV_2PI_F 0.15915494309189535f
#define EPSF 1e-6f
#define DTF 0.01f
#define KCOUP 2.0f
#define CPL (DTF * KCOUP * INV_2PI_F)   // coupling gain in revolutions domain

// ---- GEMM geometry ----
#define BM 128
#define BN 96
#define KITERS 32                 // 2048 / 64, BK=64
#define NTILES 7                  // 672 / 96, exact
#define GTHREADS 256
#define B_TILE_BYTES (BN * 128)   // 12288 (bf16 B image)
#define A_TILE_BYTES (BM * 256)   // 32768 (f32 A tile)
#define WCHUNK (672 * 128)        // 86016 bytes per K-chunk of B image
#define W_IMG_BYTES ((size_t)KITERS * WCHUNK)   // 2,752,512
#define WS_NEED W_IMG_BYTES

typedef __attribute__((ext_vector_type(8)))  __bf16         bf16x8;
typedef __attribute__((ext_vector_type(8)))  unsigned short ushort8v;
typedef __attribute__((ext_vector_type(16))) float          f32x16;

__device__ __forceinline__ unsigned short f2bf(float f) {
  unsigned u = __builtin_bit_cast(unsigned, f);
  u = (u + 0x7FFFu + ((u >> 16) & 1u)) >> 16;   // RNE
  return (unsigned short)u;
}

// pack 2 f32 -> 2 bf16 (RNE, same rounding as f2bf), S0 -> low16, S1 -> high16
__device__ __forceinline__ unsigned cvtpk(float lo, float hi) {
  unsigned r;
  asm("v_cvt_pk_bf16_f32 %0, %1, %2" : "=v"(r) : "v"(lo), "v"(hi));
  return r;
}

// ---------- prep_w: W (f32) -> swizzled bf16 image [t][col][slot*16B] ----------
__global__ void prep_w(const float* __restrict__ Wd, const float* __restrict__ Wt,
                       const float* __restrict__ Wg, char* __restrict__ wbB) {
  int id = blockIdx.x * 256 + threadIdx.x;      // 672 * 64 total
  if (id >= 672 * 64) return;
  int col = id >> 6;
  int rem = id & 63, t = rem >> 1, h = rem & 1;
  const float* src = (col < 32)  ? Wd + (size_t)col * 2048
                   : (col < 160) ? Wt + (size_t)(col - 32) * 2048
                                 : Wg + (size_t)(col - 160) * 2048;
  src += t * 64 + h * 32;
  char* dst = wbB + ((size_t)t * 672 + col) * 128;
  #pragma unroll
  for (int s4 = 0; s4 < 4; s4++) {
    float4 a = ((const float4*)src)[s4 * 2];
    float4 b = ((const float4*)src)[s4 * 2 + 1];
    ushort8v v;
    v[0] = f2bf(a.x); v[1] = f2bf(a.y); v[2] = f2bf(a.z); v[3] = f2bf(a.w);
    v[4] = f2bf(b.x); v[5] = f2bf(b.y); v[6] = f2bf(b.z); v[7] = f2bf(b.w);
    int slot = (h * 4 + s4) ^ (col & 7);
    *(ushort8v*)(dst + slot * 16) = v;
  }
}

// ---------- K1: z = x @ W^T. A staged f32 via gll (coalesced), cvt on LDS read ----------
__launch_bounds__(GTHREADS, 3)
__global__ void gemm(const float* __restrict__ x, const char* __restrict__ wbB,
                     float* __restrict__ z) {
  __shared__ __align__(16) char smem[B_TILE_BYTES + A_TILE_BYTES];   // 44 KB
  char* Bs = smem;
  char* As = smem + B_TILE_BYTES;

  const int tid = threadIdx.x;
  const int wid = tid >> 6, lane = tid & 63;

  // XCD-aware: each XCD owns 32 exclusive row panels; 7 n-tiles of a panel adjacent
  const int bid = blockIdx.x;
  const int xcd = bid & 7, j = bid >> 3;
  const int panel = xcd * 32 + j / NTILES;
  const int n = j % NTILES;
  const size_t row0 = (size_t)panel * BM;

  f32x16 acc[3];
  #pragma unroll
  for (int f = 0; f < 3; f++)
    #pragma unroll
    for (int jj = 0; jj < 16; jj++) acc[f][jj] = 0.f;

  // A f32 staging: 8 rounds; round rnd covers rows rnd*16 + (tid>>4).
  // dest = As + rnd*4096 + tid*16 (linear, row-major [128][64 f32]).
  // phys slot = tid&15; store logical slot (tid&15)^(row&15) there (pre-swizzled src).
  // (row&15) == (tid>>4) for every round -> per-thread constant source column.
  const int arow_s = tid >> 4;                          // 0..15
  const int aslot_log = (tid & 15) ^ arow_s;            // logical 16B-slot to fetch
  const float* asrc0 = x + (row0 + arow_s) * 2048 + aslot_log * 4;

  // frag read: row = wid*32 + (lane&31); logical slot ls = s4*4 + (lane>>5)*2
  const int arf = wid * 32 + (lane & 31);
  const float* afbase = (const float*)(As + arf * 256);
  const int arfx = arf & 15;

  for (int t = 0; t < KITERS; t++) {
    __syncthreads();                              // prev compute done, LDS free
    {
      const char* bsrc = wbB + (size_t)t * WCHUNK + n * B_TILE_BYTES;
      #pragma unroll
      for (int rnd = 0; rnd < 3; rnd++) {
        int off = rnd * 4096 + tid * 16;
        __builtin_amdgcn_global_load_lds(
            (const __attribute__((address_space(1))) void*)(bsrc + off),
            (__attribute__((address_space(3))) void*)(Bs + off), 16, 0, 0);
      }
      const float* asrc = asrc0 + t * 64;
      #pragma unroll
      for (int rnd = 0; rnd < 8; rnd++) {
        __builtin_amdgcn_global_load_lds(
            (const __attribute__((address_space(1))) void*)(asrc + (size_t)rnd * 16 * 2048),
            (__attribute__((address_space(3))) void*)(As + rnd * 4096 + tid * 16), 16, 0, 0);
      }
    }
    __syncthreads();                              // staged tiles visible
    #pragma unroll
    for (int s4 = 0; s4 < 4; s4++) {
      int sl = s4 * 2 + (lane >> 5);              // bf16-slot index (for B)
      // A: two b128 reads (8 f32, k = s4*16 + hk*8 .. +7), swizzled slots
      int ls = s4 * 4 + (lane >> 5) * 2;
      int p0 = ls ^ arfx;
      int p1 = p0 ^ 1;                            // (ls+1)^arfx, ls even
      float4 lo = *(const float4*)(afbase + p0 * 4);
      float4 hi = *(const float4*)(afbase + p1 * 4);
      unsigned d0 = cvtpk(lo.x, lo.y), d1 = cvtpk(lo.z, lo.w);
      unsigned d2 = cvtpk(hi.x, hi.y), d3 = cvtpk(hi.z, hi.w);
      uint4 u = {d0, d1, d2, d3};
      bf16x8 af = __builtin_bit_cast(bf16x8, u);
      #pragma unroll
      for (int fn = 0; fn < 3; fn++) {
        int c = fn * 32 + (lane & 31);
        bf16x8 bfr = __builtin_bit_cast(bf16x8,
            *(const ushort8v*)(Bs + c * 128 + ((sl ^ (c & 7)) << 4)));
        acc[fn] = __builtin_amdgcn_mfma_f32_32x32x16_bf16(af, bfr, acc[fn], 0, 0, 0);
      }
    }
  }

  #pragma unroll
  for (int fn = 0; fn < 3; fn++) {
    int col = n * 96 + fn * 32 + (lane & 31);
    #pragma unroll
    for (int reg = 0; reg < 16; reg++) {
      int row = wid * 32 + (reg & 3) + ((reg >> 2) << 3) + ((lane >> 5) << 2);
      z[(row0 + row) * 672 + col] = acc[fn][reg];
    }
  }
}

// ---------- wave-wide f32 sum: 4 DPP levels + ds_swizzle xor16 + shfl xor32 ----------
__device__ __forceinline__ float wave_sum(float v) {
  v += __builtin_bit_cast(float, __builtin_amdgcn_update_dpp(
         0, __builtin_bit_cast(int, v), 0xB1, 0xF, 0xF, true));   // quad_perm xor1
  v += __builtin_bit_cast(float, __builtin_amdgcn_update_dpp(
         0, __builtin_bit_cast(int, v), 0x4E, 0xF, 0xF, true));   // quad_perm xor2
  v += __builtin_bit_cast(float, __builtin_amdgcn_update_dpp(
         0, __builtin_bit_cast(int, v), 0x141, 0xF, 0xF, true));  // row_half_mirror
  v += __builtin_bit_cast(float, __builtin_amdgcn_update_dpp(
         0, __builtin_bit_cast(int, v), 0x140, 0xF, 0xF, true));  // row_mirror
  v += __builtin_bit_cast(float, __builtin_amdgcn_ds_swizzle(
         __builtin_bit_cast(int, v), 0x401F));                    // xor16
  v += __shfl_xor(v, 32);                                         // cross-32
  return v;
}

// ---------- K2: Kuramoto dynamics + in-place scale of d_out ----------
#define ZSTR 164
#define DROWS 32
__launch_bounds__(256, 6)
__global__ void dyn_scale(float* __restrict__ z,
                          const float* __restrict__ pdt_p,
                          const float* __restrict__ ptg_p) {
  __shared__ float zdt[DROWS * ZSTR];
  __shared__ float Fbuf[2 * DROWS];
  const int tid = threadIdx.x;
  const int wid = tid >> 6, lane = tid & 63;
  const size_t row0 = (size_t)blockIdx.x * DROWS;

  for (int i = tid; i < DROWS * 40; i += 256) {
    int row = i / 40, c4 = i - row * 40;
    float4 v = *(const float4*)(z + (row0 + row) * 672 + c4 * 4);
    *(float4*)(&zdt[row * ZSTR + c4 * 4]) = v;
  }
  __syncthreads();

  const float pdt = fminf(fmaxf(pdt_p[0], 0.f), 1.f);
  const float ptg = fminf(fmaxf(ptg_p[0], 0.f), 1.f);

  for (int rr = 0; rr < 8; rr++) {
    int row = wid * 8 + rr;
    // phases in revolutions: q = p / 2π;  sin(p) = v_sin(fract(q))
    float pd  = ((lane < 32) ? zdt[row * ZSTR + lane] : 0.f) * INV_2PI_F;
    float pt0 = zdt[row * ZSTR + 32 + lane] * INV_2PI_F;
    float pt1 = zdt[row * ZSTR + 96 + lane] * INV_2PI_F;
    float Ft = 1.f, Fg = 1.f;
    for (int s = 0; s < 10; s++) {
      float qd = pd - floorf(pd), q0 = pt0 - floorf(pt0), q1 = pt1 - floorf(pt1);
      float sd, cd, s0, c0, s1, c1;
      asm("v_sin_f32 %0, %1" : "=v"(sd) : "v"(qd));
      asm("v_cos_f32 %0, %1" : "=v"(cd) : "v"(qd));
      asm("v_sin_f32 %0, %1" : "=v"(s0) : "v"(q0));
      asm("v_cos_f32 %0, %1" : "=v"(c0) : "v"(q0));
      asm("v_sin_f32 %0, %1" : "=v"(s1) : "v"(q1));
      asm("v_cos_f32 %0, %1" : "=v"(c1) : "v"(q1));
      float Cd = wave_sum((lane < 32) ? cd : 0.f) * (1.f / 32.f);
      float Sd = wave_sum((lane < 32) ? sd : 0.f) * (1.f / 32.f);
      float Ct = wave_sum(c0 + c1) * (1.f / 128.f);
      float St = wave_sum(s0 + s1) * (1.f / 128.f);
      pd  += DTF * 2.f + CPL * (Sd * cd - Cd * sd);
      pt0 += DTF * 6.f + CPL * (St * c0 - Ct * s0);
      pt1 += DTF * 6.f + CPL * (St * c1 - Ct * s1);
      float rdm = sqrtf(Cd * Cd + Sd * Sd) + EPSF;
      float rtm = sqrtf(Ct * Ct + St * St) + EPSF;
      Ft *= (1.f + DTF * pdt * (Cd / rdm));
      Fg *= (1.f + DTF * ptg * (Ct / rtm));
    }
    if (lane == 0) { Fbuf[row] = Ft; Fbuf[DROWS + row] = Fg; }
  }
  __syncthreads();

  // scale: cols 0..159 come from the LDS copy (no global re-read); rest from global
  for (int i = tid; i < DROWS * 168; i += 256) {
    int row = i / 168, c4 = i - row * 168;
    float4* p = (float4*)(z + (row0 + row) * 672 + c4 * 4);
    float4 v = (c4 < 40) ? *(const float4*)(&zdt[row * ZSTR + c4 * 4]) : *p;
    float f = (c4 < 8) ? 1.f : (c4 < 40 ? Fbuf[row] : Fbuf[DROWS + row]);
    v.x = fmaxf(fmaxf(fabsf(v.x), EPSF) * f, EPSF);
    v.y = fmaxf(fmaxf(fabsf(v.y), EPSF) * f, EPSF);
    v.z = fmaxf(fmaxf(fabsf(v.z), EPSF) * f, EPSF);
    v.w = fmaxf(fmaxf(fabsf(v.w), EPSF) * f, EPSF);
    *p = v;
  }
}

extern "C" void kernel_launch(void* const* d_in, const int* in_sizes, int n_in,
                              void* d_out, int out_size, void* d_ws, size_t ws_size,
                              hipStream_t stream) {
  const float* x   = (const float*)d_in[0];
  const float* Wd  = (const float*)d_in[1];
  const float* Wt  = (const float*)d_in[2];
  const float* Wg  = (const float*)d_in[3];
  const float* pdt = (const float*)d_in[4];
  const float* ptg = (const float*)d_in[5];
  float* outp = (float*)d_out;
  char* wbB = (char*)d_ws;

  if (ws_size < WS_NEED) return;

  const int Brows = in_sizes[0] / 2048;           // 32768
  prep_w<<<(672 * 64 + 255) / 256, 256, 0, stream>>>(Wd, Wt, Wg, wbB);
  gemm<<<(Brows / BM) * NTILES, GTHREADS, 0, stream>>>(x, wbB, outp);
  dyn_scale<<<Brows / DROWS, 256, 0, stream>>>(outp, pdt, ptg);
}